// Round 4
// baseline (707.475 us; speedup 1.0000x reference)
//
#include <hip/hip_runtime.h>

// GRU encoder: B=64, T=512, F=64, H=256, D=64.
//   k1: xproj = x @ kernel + bias -> f16 in d_ws, dot2-based GEMM.
//   k2: per-batch scan, 64 blocks x 512 threads (8 waves/CU -> 256-VGPR cap).
//       Thread (c=tid>>8, col=tid&255) holds W_rec k-half c for columns
//       {col,col+256,col+512}: 192 f16 pairs in VGPRs (fits cap with slack,
//       avoiding the AGPR demotion + v_accvgpr_read tax seen at 1024 thr).
//       Gate thread i owns its z/r/h partials in-reg; only 3 LDS reads/step.

typedef _Float16 half2_t __attribute__((ext_vector_type(2)));
typedef _Float16 f16x4_t __attribute__((ext_vector_type(4)));

#define LOG2E 1.4426950408889634f

__device__ __forceinline__ float fast_sigmoid(float x) {
  float e = __builtin_amdgcn_exp2f(-x * LOG2E);
  return __builtin_amdgcn_rcpf(1.0f + e);
}
__device__ __forceinline__ float fast_tanh(float x) {
  float e = __builtin_amdgcn_exp2f(x * (2.0f * LOG2E));
  return 1.0f - 2.0f * __builtin_amdgcn_rcpf(1.0f + e);
}

// ---------------------------------------------------------------------------
// Kernel 1: xproj GEMM.  C(32768x768) = A(32768x64) @ B(64x768) + bias.
// f16-pair LDS staging, v_dot2_f32_f16 inner loop, 8x(4+4) microtile.
// ---------------------------------------------------------------------------
__global__ __launch_bounds__(256, 4) void xproj_gemm(
    const float* __restrict__ x, const float* __restrict__ kmat,
    const float* __restrict__ bias, _Float16* __restrict__ xp) {
  __shared__ half2_t As2[32][132];  // [kpair][row]
  __shared__ half2_t Bs2[32][132];  // [kpair][col]
  const int tid = threadIdx.x;
  const int rb = blockIdx.x * 128;
  const int cb = blockIdx.y * 128;

  {
    const int k4 = (tid & 15) * 4;
    const int r0 = tid >> 4;
#pragma unroll
    for (int p = 0; p < 8; ++p) {
      int r = r0 + p * 16;
      float4 v = *(const float4*)(x + (size_t)(rb + r) * 64 + k4);
      half2_t lo, hi;
      lo[0] = (_Float16)v.x; lo[1] = (_Float16)v.y;
      hi[0] = (_Float16)v.z; hi[1] = (_Float16)v.w;
      As2[k4 / 2][r] = lo;
      As2[k4 / 2 + 1][r] = hi;
    }
  }
  {
    const int c4 = (tid & 31) * 4;
    const int kp0 = tid >> 5;
#pragma unroll
    for (int p = 0; p < 4; ++p) {
      int kp = kp0 + p * 8;
      float4 va = *(const float4*)(kmat + (size_t)(2 * kp) * 768 + cb + c4);
      float4 vb = *(const float4*)(kmat + (size_t)(2 * kp + 1) * 768 + cb + c4);
      half2_t o0, o1, o2, o3;
      o0[0] = (_Float16)va.x; o0[1] = (_Float16)vb.x;
      o1[0] = (_Float16)va.y; o1[1] = (_Float16)vb.y;
      o2[0] = (_Float16)va.z; o2[1] = (_Float16)vb.z;
      o3[0] = (_Float16)va.w; o3[1] = (_Float16)vb.w;
      Bs2[kp][c4 + 0] = o0;
      Bs2[kp][c4 + 1] = o1;
      Bs2[kp][c4 + 2] = o2;
      Bs2[kp][c4 + 3] = o3;
    }
  }
  __syncthreads();

  const int tx = tid & 15, ty = tid >> 4;
  const int r0 = ty * 8;
  const int c0 = tx * 4;
  float acc[8][8];
  {
    float4 b0 = *(const float4*)(bias + cb + c0);
    float4 b1 = *(const float4*)(bias + cb + 64 + c0);
    float bz[8] = {b0.x, b0.y, b0.z, b0.w, b1.x, b1.y, b1.z, b1.w};
#pragma unroll
    for (int i = 0; i < 8; ++i)
#pragma unroll
      for (int j = 0; j < 8; ++j) acc[i][j] = bz[j];
  }

#pragma unroll 2
  for (int kp = 0; kp < 32; ++kp) {
    half2_t a2[8], b2[8];
    *(int4*)(&a2[0]) = *(const int4*)(&As2[kp][r0]);
    *(int4*)(&a2[4]) = *(const int4*)(&As2[kp][r0 + 4]);
    *(int2*)(&b2[0]) = *(const int2*)(&Bs2[kp][c0]);
    *(int2*)(&b2[2]) = *(const int2*)(&Bs2[kp][c0 + 2]);
    *(int2*)(&b2[4]) = *(const int2*)(&Bs2[kp][64 + c0]);
    *(int2*)(&b2[6]) = *(const int2*)(&Bs2[kp][64 + c0 + 2]);
#pragma unroll
    for (int i = 0; i < 8; ++i)
#pragma unroll
      for (int j = 0; j < 8; ++j)
        acc[i][j] = __builtin_amdgcn_fdot2(a2[i], b2[j], acc[i][j], false);
  }

#pragma unroll
  for (int i = 0; i < 8; ++i) {
    f16x4_t o0, o1;
#pragma unroll
    for (int j = 0; j < 4; ++j) {
      o0[j] = (_Float16)acc[i][j];
      o1[j] = (_Float16)acc[i][4 + j];
    }
    _Float16* dst = xp + (size_t)(rb + r0 + i) * 768 + cb;
    *(f16x4_t*)(dst + c0) = o0;
    *(f16x4_t*)(dst + 64 + c0) = o1;
  }
}

// ---------------------------------------------------------------------------
// Kernel 2: GRU scan. One block per batch row. 512 threads = 8 waves.
// c = tid>>8 (k-half), col = tid&255. Weights: w2[q][j] = W_rec[c*128+2j..+1]
// [col+q*256] as f16 pairs -> 192 VGPRs. Gate threads (c=0) keep their own
// partials in registers; c=1 partials cross via LDS (3 reads/step).
// ---------------------------------------------------------------------------
__global__ __launch_bounds__(512, 2) void gru_scan(
    const _Float16* __restrict__ xp, const float* __restrict__ wr,
    const float* __restrict__ dw, const float* __restrict__ db,
    float* __restrict__ out, float* __restrict__ state) {
  __shared__ float part[3 * 256];  // c=1 partials
  __shared__ float hbuf[256];
  __shared__ alignas(16) _Float16 hhalf[256];

  const int tid = threadIdx.x;
  const int b = blockIdx.x;
  const int c = tid >> 8;     // k-half 0/1
  const int col = tid & 255;  // column within gate

  // --- W_rec fragment -> 192 f16 pairs in VGPRs (coalesced stride-768 rows)
  half2_t w2[3][64];
#pragma unroll
  for (int q = 0; q < 3; ++q) {
    const float* wp = wr + (size_t)(c * 128) * 768 + col + q * 256;
#pragma unroll
    for (int j = 0; j < 64; ++j) {
      float wa = wp[(size_t)(2 * j) * 768];
      float wb = wp[(size_t)(2 * j + 1) * 768];
      half2_t p;
      p[0] = (_Float16)wa;
      p[1] = (_Float16)wb;
      w2[q][j] = p;
    }
  }

  if (tid < 256) hhalf[tid] = (_Float16)0.0f;
  __syncthreads();

  const _Float16* xpb = xp + (size_t)b * 512 * 768;
  float* outb = out + (size_t)b * 512 * 256;
  const int4* hp = (const int4*)hhalf + c * 16;  // this thread's k-half of h
  float hprev = 0.0f;

  for (int t = 0; t < 512; ++t) {
    // gate threads load their x values straight into registers
    float xz = 0.0f, xr = 0.0f, xh = 0.0f;
    if (tid < 256) {
      const _Float16* xr0 = xpb + (size_t)t * 768 + tid;
      xz = (float)xr0[0];
      xr = (float)xr0[256];
      xh = (float)xr0[512];
    }

    // --- matvec over this thread's k-half (16 int4 broadcast reads of h)
    float a0 = 0.0f, a1 = 0.0f, a2 = 0.0f;
    int4 hv = hp[0];
#pragma unroll
    for (int g = 0; g < 16; ++g) {
      int4 hn = hv;
      if (g < 15) hn = hp[g + 1];
      half2_t p0 = __builtin_bit_cast(half2_t, hv.x);
      half2_t p1 = __builtin_bit_cast(half2_t, hv.y);
      half2_t p2 = __builtin_bit_cast(half2_t, hv.z);
      half2_t p3 = __builtin_bit_cast(half2_t, hv.w);
      a0 = __builtin_amdgcn_fdot2(p0, w2[0][g * 4 + 0], a0, false);
      a0 = __builtin_amdgcn_fdot2(p1, w2[0][g * 4 + 1], a0, false);
      a0 = __builtin_amdgcn_fdot2(p2, w2[0][g * 4 + 2], a0, false);
      a0 = __builtin_amdgcn_fdot2(p3, w2[0][g * 4 + 3], a0, false);
      a1 = __builtin_amdgcn_fdot2(p0, w2[1][g * 4 + 0], a1, false);
      a1 = __builtin_amdgcn_fdot2(p1, w2[1][g * 4 + 1], a1, false);
      a1 = __builtin_amdgcn_fdot2(p2, w2[1][g * 4 + 2], a1, false);
      a1 = __builtin_amdgcn_fdot2(p3, w2[1][g * 4 + 3], a1, false);
      a2 = __builtin_amdgcn_fdot2(p0, w2[2][g * 4 + 0], a2, false);
      a2 = __builtin_amdgcn_fdot2(p1, w2[2][g * 4 + 1], a2, false);
      a2 = __builtin_amdgcn_fdot2(p2, w2[2][g * 4 + 2], a2, false);
      a2 = __builtin_amdgcn_fdot2(p3, w2[2][g * 4 + 3], a2, false);
      hv = hn;
    }
    if (tid >= 256) {  // c=1 waves export partials
      part[col] = a0;
      part[256 + col] = a1;
      part[512 + col] = a2;
    }
    __syncthreads();

    // --- gates on waves 0..3; deferred h(t-1) store overlaps LDS latency
    if (tid < 256) {
      const int i = tid;
      if (t) outb[(size_t)(t - 1) * 256 + i] = hprev;
      float rz = a0 + part[i];
      float rr = a1 + part[256 + i];
      float rh = a2 + part[512 + i];
      float z = fast_sigmoid(xz + rz);
      float r = fast_sigmoid(xr + rr);
      float hh = fast_tanh(xh + r * rh);
      float hnew = z * hprev + (1.0f - z) * hh;
      hprev = hnew;
      hhalf[i] = (_Float16)hnew;
    }
    __syncthreads();
  }

  if (tid < 256) {
    outb[(size_t)511 * 256 + tid] = hprev;
    hbuf[tid] = hprev;
  }
  __syncthreads();

  // --- dense head: state[b,:] = tanh(h_last @ dense_w + dense_b)
  if (tid < 64) {
    float acc = db[tid];
#pragma unroll 8
    for (int k = 0; k < 256; ++k) acc = fmaf(hbuf[k], dw[k * 64 + tid], acc);
    state[(size_t)b * 64 + tid] = fast_tanh(acc);
  }
}

// ---------------------------------------------------------------------------
extern "C" void kernel_launch(void* const* d_in, const int* in_sizes, int n_in,
                              void* d_out, int out_size, void* d_ws,
                              size_t ws_size, hipStream_t stream) {
  const float* x = (const float*)d_in[0];     // (64,512,64)
  const float* kmat = (const float*)d_in[1];  // (64,768)
  const float* wr = (const float*)d_in[2];    // (256,768)
  const float* bias = (const float*)d_in[3];  // (768,)
  const float* dw = (const float*)d_in[4];    // (256,64)
  const float* db = (const float*)d_in[5];    // (64,)

  float* out = (float*)d_out;                   // (64,512,256)
  float* state = out + (size_t)64 * 512 * 256;  // (64,64)
  _Float16* xp = (_Float16*)d_ws;               // 64*512*768 f16 = 48 MiB

  dim3 gg(32768 / 128, 768 / 128);
  xproj_gemm<<<gg, 256, 0, stream>>>(x, kmat, bias, xp);
  gru_scan<<<64, 512, 0, stream>>>(xp, wr, dw, db, out, state);
}